// Round 1
// baseline (594.186 us; speedup 1.0000x reference)
//
#include <hip/hip_runtime.h>

// ---------------------------------------------------------------------------
// Tensor_CSPNet forward, restructured:
//   out[b,o] = sum_h <G[o,h], log(V_h^T X[b,h] V_h + D_h)> + const[o]
// ReEig stages are provably no-ops (all eigenvalues >= 0.5 >> 1e-4).
// Eigensolve: one-sided Hestenes Jacobi, pair-per-lane in registers,
// 4 matrices per wave (16-lane rows, 11 active lanes each), DPP migration.
// ---------------------------------------------------------------------------

#define WS_S     0                      // 484 floats  : S = rm^-1/2 @ bn^1/2
#define WS_CONST 484                    // 4 floats    : fc_w@conv_b + fc_b
#define WS_VT    512                    // 27*484      : Vt[h][j][k] = V_h[k][j]
#define WS_D     (512 + 27*484)         // 27*484      : D_h row-major (sym)
#define WS_G     (512 + 2*27*484)       // 4*27*528    : G[o][h], rows padded to 24
#define G_STRIDE 528
#define NSWEEP   7

static __device__ __forceinline__ float dpp_shl1(float x) { // lane m <- lane m+1 (within 16-row)
  return __int_as_float(__builtin_amdgcn_mov_dpp(__float_as_int(x), 0x101, 0xf, 0xf, true));
}
static __device__ __forceinline__ float dpp_shr1(float x) { // lane m <- lane m-1 (within 16-row)
  return __int_as_float(__builtin_amdgcn_mov_dpp(__float_as_int(x), 0x111, 0xf, 0xf, true));
}

// ---------------- prep1: S = rm^{-1/2} @ bn^{1/2} via Newton-Schulz ----------
__global__ void prep1_kernel(const float* __restrict__ rm, const float* __restrict__ bn,
                             const float* __restrict__ fc_w, const float* __restrict__ conv_b,
                             const float* __restrict__ fc_b, float* __restrict__ ws) {
  __shared__ float A[484], Y[484], Z[484], T[484], Y2[484], Z2[484], Gp[484], Gn[484];
  __shared__ float sh_th;
  int tid = threadIdx.x;
  for (int pass = 0; pass < 2; ++pass) {
    const float* src = (pass == 0) ? bn : rm;
    for (int idx = tid; idx < 484; idx += 256) A[idx] = src[idx];
    __syncthreads();
    if (tid == 0) { float tr = 0.f; for (int i = 0; i < 22; ++i) tr += A[i*23]; sh_th = 0.5f*tr; }
    __syncthreads();
    float th = sh_th;
    for (int idx = tid; idx < 484; idx += 256) {
      int i = idx/22, j = idx%22;
      Y[idx] = A[idx]/th;
      Z[idx] = (i==j) ? 1.0f : 0.0f;
    }
    __syncthreads();
    for (int it = 0; it < 16; ++it) {
      for (int idx = tid; idx < 484; idx += 256) {
        int i = idx/22, j = idx%22;
        float s = 0.f;
        for (int k = 0; k < 22; ++k) s += Z[i*22+k]*Y[k*22+j];
        T[idx] = ((i==j)?1.5f:0.0f) - 0.5f*s;
      }
      __syncthreads();
      for (int idx = tid; idx < 484; idx += 256) {
        int i = idx/22, j = idx%22;
        float sy = 0.f, sz = 0.f;
        for (int k = 0; k < 22; ++k) { sy += Y[i*22+k]*T[k*22+j]; sz += T[i*22+k]*Z[k*22+j]; }
        Y2[idx] = sy; Z2[idx] = sz;
      }
      __syncthreads();
      for (int idx = tid; idx < 484; idx += 256) { Y[idx] = Y2[idx]; Z[idx] = Z2[idx]; }
      __syncthreads();
    }
    float sth = sqrtf(th);
    for (int idx = tid; idx < 484; idx += 256) {
      if (pass == 0) Gp[idx] = Y[idx]*sth;   // bn^{1/2}
      else           Gn[idx] = Z[idx]/sth;   // rm^{-1/2}
    }
    __syncthreads();
  }
  for (int idx = tid; idx < 484; idx += 256) {
    int i = idx/22, j = idx%22;
    float s = 0.f;
    for (int k = 0; k < 22; ++k) s += Gn[i*22+k]*Gp[k*22+j];
    ws[WS_S + idx] = s;
  }
  if (tid < 4) {
    float s = 0.f;
    for (int c = 0; c < 48; ++c) s += fc_w[tid*48+c]*conv_b[c];
    ws[WS_CONST + tid] = s + fc_b[tid];
  }
}

// ---------------- prep2: per-h Vt, D, G ------------------------------------
__global__ void prep2_kernel(const float* __restrict__ W1, const float* __restrict__ W2,
                             const float* __restrict__ conv_w, const float* __restrict__ fc_w,
                             float* __restrict__ ws) {
  __shared__ float sW1[1024], sW2[704], sS[484], sU[704], sE[220], sG[1936];
  int h = blockIdx.x, tid = threadIdx.x;
  for (int idx = tid; idx < 1024; idx += 256) sW1[idx] = W1[h*1024+idx];
  for (int idx = tid; idx < 704;  idx += 256) sW2[idx] = W2[h*704+idx];
  for (int idx = tid; idx < 484;  idx += 256) sS[idx]  = ws[WS_S+idx];
  __syncthreads();
  // U = W1 @ W2  (32x22)
  for (int idx = tid; idx < 704; idx += 256) {
    int n = idx/22, j = idx%22;
    float s = 0.f;
    for (int k = 0; k < 32; ++k) s += sW1[n*32+k]*sW2[k*22+j];
    sU[idx] = s;
  }
  __syncthreads();
  // Vt[j][k] = (U_top @ S)[k][j]
  for (int idx = tid; idx < 484; idx += 256) {
    int k = idx/22, j = idx%22;
    float s = 0.f;
    for (int l = 0; l < 22; ++l) s += sU[k*22+l]*sS[l*22+j];
    ws[WS_VT + h*484 + j*22 + k] = s;
  }
  // E = U_bot @ S (10x22)
  for (int idx = tid; idx < 220; idx += 256) {
    int e = idx/22, j = idx%22;
    float s = 0.f;
    for (int l = 0; l < 22; ++l) s += sU[(22+e)*22+l]*sS[l*22+j];
    sE[idx] = s;
  }
  __syncthreads();
  // D = E^T E (22x22, symmetric)
  for (int idx = tid; idx < 484; idx += 256) {
    int i = idx/22, j = idx%22;
    float s = 0.f;
    for (int e = 0; e < 10; ++e) s += sE[e*22+i]*sE[e*22+j];
    ws[WS_D + h*484 + idx] = s;
  }
  // G[o][h] = sym( sum_c fc_w[o,c] * conv_w[c,0,wi, bi*484 + i*22+j] )
  int wi = h/9, bi = h%9;
  for (int idx = tid; idx < 1936; idx += 256) {
    int o = idx/484, r = idx%484;
    float s = 0.f;
    for (int c = 0; c < 48; ++c) s += fc_w[o*48+c]*conv_w[c*13068 + wi*4356 + bi*484 + r];
    sG[idx] = s;
  }
  __syncthreads();
  for (int idx = tid; idx < 1936; idx += 256) {
    int o = idx/484, r = idx%484, i = r/22, j = r%22;
    float v = 0.5f*(sG[o*484+i*22+j] + sG[o*484+j*22+i]);
    ws[WS_G + (o*27+h)*G_STRIDE + i*24 + j] = v;
  }
}

// ---------------- main: P4 build + one-sided Jacobi + projection -----------
__global__ void __launch_bounds__(64) main_kernel(const float* __restrict__ x,
                                                  const float* __restrict__ ws,
                                                  float* __restrict__ out) {
  __shared__ float sX[1936], sV[1936];
  const int lane = threadIdx.x;
  const int g = lane >> 4, m = lane & 15;
  const int mm = (m < 10) ? m : 10;          // clamp inactive lanes to safe data
  const int id = blockIdx.x*4 + g;           // 13824 = 3456*4 exactly
  const int b = id / 27, h = id - b*27;

  // stage X (4 consecutive matrices are contiguous in x)
  {
    const float4* xg = (const float4*)(x + (size_t)blockIdx.x * 1936);
    float4* dX = (float4*)sX;
    #pragma unroll
    for (int t = 0; t < 8; ++t) { int fi = t*64 + lane; if (fi < 484) dX[fi] = xg[fi]; }
  }
  // stage Vt for this group's h
  {
    const float4* vg = (const float4*)(ws + WS_VT + h*484);
    float4* dV = (float4*)(sV + g*484);
    #pragma unroll
    for (int t = 0; t < 8; ++t) { int qi = t*16 + m; if (qi < 121) dV[qi] = vg[qi]; }
  }
  __syncthreads();

  // vrows: V columns 2mm, 2mm+1  (rows 2mm,2mm+1 of Vt, 44 contiguous floats)
  float vr[44];
  {
    const float4* vb = (const float4*)(ws + WS_VT + h*484 + mm*44);
    #pragma unroll
    for (int j = 0; j < 11; ++j) {
      float4 q = vb[j];
      vr[4*j+0]=q.x; vr[4*j+1]=q.y; vr[4*j+2]=q.z; vr[4*j+3]=q.w;
    }
  }
  // MM1: t[k] = sum_l X[k][l]*V[l][2mm(+1)]
  float tL[22], tR[22];
  {
    const float2* X2 = (const float2*)sX;
    #pragma unroll
    for (int k = 0; k < 22; ++k) {
      float aL = 0.f, aR = 0.f;
      #pragma unroll
      for (int c = 0; c < 11; ++c) {
        float2 xv = X2[242*g + 11*k + c];
        aL += xv.x*vr[2*c]    + xv.y*vr[2*c+1];
        aR += xv.x*vr[22+2*c] + xv.y*vr[22+2*c+1];
      }
      tL[k] = aL; tR[k] = aR;
    }
  }
  // MM2 + D: w[i] = D[i][2mm(+1)] + sum_k Vt[i][k]*t[k]   (columns of P4)
  float wL[22], wR[22];
  {
    const float4* db = (const float4*)(ws + WS_D + h*484 + mm*44);
    float dr[44];
    #pragma unroll
    for (int j = 0; j < 11; ++j) {
      float4 q = db[j];
      dr[4*j+0]=q.x; dr[4*j+1]=q.y; dr[4*j+2]=q.z; dr[4*j+3]=q.w;
    }
    const float2* V2 = (const float2*)sV;
    #pragma unroll
    for (int i = 0; i < 22; ++i) {
      float aL = dr[i], aR = dr[22+i];
      #pragma unroll
      for (int c = 0; c < 11; ++c) {
        float2 vv = V2[242*g + 11*i + c];
        aL += vv.x*tL[2*c] + vv.y*tL[2*c+1];
        aR += vv.x*tR[2*c] + vv.y*tR[2*c+1];
      }
      wL[i] = aL; wR[i] = aR;
    }
  }

  // one-sided Jacobi (Hestenes), pair-per-lane, circle-method migration.
  // cycle: R0->R1->...->R10->L10->L9->...->L1->R0, L0 pinned. 21 rounds = full cycle.
  const bool is0 = (m == 0), is10 = (m == 10);
  #pragma unroll 1
  for (int sweep = 0; sweep < NSWEEP; ++sweep) {
    float nL = 0.f, nR = 0.f;                 // fresh norms each sweep
    #pragma unroll
    for (int i = 0; i < 22; ++i) { nL += wL[i]*wL[i]; nR += wR[i]*wR[i]; }
    #pragma unroll 1
    for (int r = 0; r < 21; ++r) {
      float d = 0.f;
      #pragma unroll
      for (int i = 0; i < 22; ++i) d += wL[i]*wR[i];
      float ad  = fabsf(d);
      float tau = (nR - nL)*0.5f*__builtin_amdgcn_rcpf(d);
      float sq  = sqrtf(1.0f + tau*tau);
      float t   = copysignf(__builtin_amdgcn_rcpf(fabsf(tau) + sq), tau);
      float c   = __builtin_amdgcn_rsqf(1.0f + t*t);
      float s   = t*c;
      bool tiny = (ad < 1e-28f);
      c = tiny ? 1.0f : c;
      s = tiny ? 0.0f : s;
      float cc = c*c, ss = s*s, cs2 = 2.0f*c*s;
      float nLn = cc*nL - cs2*d + ss*nR;
      float nRn = ss*nL + cs2*d + cc*nR;
      #pragma unroll
      for (int i = 0; i < 22; ++i) {
        float nl = c*wL[i] - s*wR[i];
        float nr = s*wL[i] + c*wR[i];
        float tl = dpp_shl1(nl);              // lane m <- newL of m+1
        float tr = dpp_shr1(nr);              // lane m <- newR of m-1
        wL[i] = is0 ? nl : (is10 ? nr : tl);
        wR[i] = is0 ? tl : tr;
      }
      {
        float tl = dpp_shl1(nLn), tr = dpp_shr1(nRn);
        nL = is0 ? nLn : (is10 ? nRn : tl);
        nR = is0 ? tl : tr;
      }
    }
  }

  // log-eig coefficients: L = sum_j (log lam_j / lam_j^2) w_j w_j^T, lam^2 = ||w||^2
  float nL = 0.f, nR = 0.f;
  #pragma unroll
  for (int i = 0; i < 22; ++i) { nL += wL[i]*wL[i]; nR += wR[i]*wR[i]; }
  const float HALF_LN2 = 0.34657359f;        // 0.5*ln(2)
  float coefL = HALF_LN2*log2f(fmaxf(nL, 1e-8f))*__builtin_amdgcn_rcpf(nL);
  float coefR = HALF_LN2*log2f(fmaxf(nR, 1e-8f))*__builtin_amdgcn_rcpf(nR);

  // projection: out[b,o] += sum_cols coef * (w^T G[o,h] w)
  #pragma unroll 1
  for (int o = 0; o < 4; ++o) {
    const float* Gptr = ws + WS_G + (o*27+h)*G_STRIDE;
    float qL = 0.f, qR = 0.f;
    #pragma unroll
    for (int k = 0; k < 22; ++k) {
      float gr[22];
      const float4* g4 = (const float4*)(Gptr + k*24);
      #pragma unroll
      for (int j = 0; j < 5; ++j) {
        float4 q = g4[j];
        gr[4*j+0]=q.x; gr[4*j+1]=q.y; gr[4*j+2]=q.z; gr[4*j+3]=q.w;
      }
      {
        float2 q2 = ((const float2*)(Gptr + k*24))[10];
        gr[20]=q2.x; gr[21]=q2.y;
      }
      float sL = 0.f, sR = 0.f;
      #pragma unroll
      for (int i = 0; i < 22; ++i) { sL += gr[i]*wL[i]; sR += gr[i]*wR[i]; }
      qL += wL[k]*sL; qR += wR[k]*sR;
    }
    float v = (m <= 10) ? (coefL*qL + coefR*qR) : 0.0f;
    v += __shfl_down(v, 8, 16);
    v += __shfl_down(v, 4, 16);
    v += __shfl_down(v, 2, 16);
    v += __shfl_down(v, 1, 16);
    if (m == 0) {
      if (h == 0) v += ws[WS_CONST + o];
      atomicAdd(out + b*4 + o, v);
    }
  }
}

extern "C" void kernel_launch(void* const* d_in, const int* in_sizes, int n_in,
                              void* d_out, int out_size, void* d_ws, size_t ws_size,
                              hipStream_t stream) {
  const float* x   = (const float*)d_in[0];
  const float* W1  = (const float*)d_in[1];
  const float* W2  = (const float*)d_in[2];
  const float* rm  = (const float*)d_in[3];
  const float* bn  = (const float*)d_in[4];
  const float* cw  = (const float*)d_in[5];
  const float* cb  = (const float*)d_in[6];
  const float* fw  = (const float*)d_in[7];
  const float* fb  = (const float*)d_in[8];
  float* out = (float*)d_out;
  float* ws  = (float*)d_ws;

  hipMemsetAsync(d_out, 0, (size_t)out_size*sizeof(float), stream);
  prep1_kernel<<<1, 256, 0, stream>>>(rm, bn, fw, cb, fb, ws);
  prep2_kernel<<<27, 256, 0, stream>>>(W1, W2, cw, fw, ws);
  main_kernel<<<3456, 64, 0, stream>>>(x, ws, out);
}